// Round 1
// baseline (2872.070 us; speedup 1.0000x reference)
//
#include <hip/hip_runtime.h>
#include <stdint.h>

// ---------------------------------------------------------------------------
// BesselConv2d on MI355X (gfx950)
//
// k1: pad+convert x (fp32 NCHW) -> xp bf16 NHWC, zero-padded to 72x72.
// k2: build Wfb[tap][ch'][cin] bf16, ch' = cout*32 + (part*16+m).
// k3: implicit-GEMM conv, fused square/group-reduce/bias epilogue.
//
// R7 change vs R6: kernel was LDS-read-pipe saturated (232KB/CU per 2077cy
// = 112 B/cy = aggregate LDS ceiling; MfmaUtil 60% == MFMA-floor/LDS-time).
// (1) B fragments now read global->VGPR directly (software-pipelined one
//     tap ahead), eliminating Bs LDS entirely: -41% LDS bytes/block-tap.
//     Fragment content identical to the old swizzled-LDS path; L1 dedups
//     the 2 waves sharing each ch-half so L2 traffic is unchanged.
// (2) As double-buffered (2x36KB): one __syncthreads per dy (9 total)
//     instead of per tap (81), staging latency hidden under 9 taps.
// Wave geometry (128px x 64ch), A swizzle, epilogue unchanged from R6.
// ---------------------------------------------------------------------------

typedef unsigned short ushort_t;
typedef __attribute__((ext_vector_type(8))) short short8;   // 8 bf16 = 4 VGPRs
typedef __attribute__((ext_vector_type(4))) float float4v;  // 4 fp32 acc

typedef const void __attribute__((address_space(1)))* gptr_t;
typedef void __attribute__((address_space(3)))* sptr_t;

__device__ __forceinline__ ushort_t f2bf(float f) {
    union { float f; uint32_t u; } v; v.f = f;
    uint32_t u = v.u;
    u += 0x7fffu + ((u >> 16) & 1u);   // round-to-nearest-even
    return (ushort_t)(u >> 16);
}

// ---------------------------------------------------------------------------
// Kernel 1: x[32][64][64][64] (NCHW fp32) -> xp[32][72][72][64] (NHWC bf16)
// ---------------------------------------------------------------------------
__global__ __launch_bounds__(256) void pad_kernel(const float* __restrict__ x,
                                                  ushort_t* __restrict__ xp) {
    __shared__ float lds[64 * 65];
    const int hp  = blockIdx.x;   // 0..71
    const int b   = blockIdx.y;   // 0..31
    const int tid = threadIdx.x;
    const int h   = hp - 4;
    const bool hvalid = (h >= 0 && h < 64);
    if (hvalid) {
        #pragma unroll
        for (int it = 0; it < 16; ++it) {
            int idx = it * 256 + tid;
            int cin = idx >> 6, w = idx & 63;
            lds[w * 65 + cin] = x[((b * 64 + cin) * 64 + h) * 64 + w];
        }
    }
    __syncthreads();
    #pragma unroll
    for (int it = 0; it < 18; ++it) {
        int o = it * 256 + tid;
        int wp = o >> 6, cin = o & 63;
        int w = wp - 4;
        float val = (hvalid && w >= 0 && w < 64) ? lds[w * 65 + cin] : 0.0f;
        xp[((b * 72 + hp) * 72 + wp) * 64 + cin] = f2bf(val);
    }
}

// ---------------------------------------------------------------------------
// Kernel 2: Wfb[t][ch'][cin] bf16, ch' = cout*32 + g, g = part*16 + m.
// ---------------------------------------------------------------------------
__global__ __launch_bounds__(256) void wf_kernel(const float* __restrict__ Tr,
                                                 const float* __restrict__ Ti,
                                                 const float* __restrict__ wr,
                                                 const float* __restrict__ wi,
                                                 ushort_t* __restrict__ Wfb) {
    __shared__ float lds[64 * 65];
    const int g   = blockIdx.x;        // 0..31
    const int t   = blockIdx.y;        // 0..80
    const int part = g >> 4, m = g & 15;
    const int tid = threadIdx.x;
    #pragma unroll
    for (int it = 0; it < 16; ++it) {
        int cc = it * 256 + tid;       // cin*64 + cout
        float acc = 0.f;
        #pragma unroll
        for (int j = 0; j < 8; ++j) {
            float tr  = Tr[(m * 81 + t) * 8 + j];
            float ti  = Ti[(m * 81 + t) * 8 + j];
            float wrv = wr[(m * 8 + j) * 4096 + cc];
            float wiv = wi[(m * 8 + j) * 4096 + cc];
            acc += (part == 0) ? (tr * wrv - ti * wiv) : (tr * wiv + ti * wrv);
        }
        lds[(cc & 63) * 65 + (cc >> 6)] = acc;
    }
    __syncthreads();
    #pragma unroll
    for (int it = 0; it < 16; ++it) {
        int o = it * 256 + tid;        // cout*64 + cin
        int cout = o >> 6, cin = o & 63;
        Wfb[(t * 2048 + cout * 32 + g) * 64 + cin] = f2bf(lds[cout * 65 + cin]);
    }
}

// ---------------------------------------------------------------------------
// Kernel 3: implicit-GEMM conv.
// Block: 256 px (4 output rows) x 128 ch. Wave: 128 px x 64 ch.
// As: double-buffered 4 padded rows [2][4][72][64] (XOR-16B-seg swizzled).
// B:  per-wave global->VGPR fragments, pipelined one tap ahead (no LDS).
// ---------------------------------------------------------------------------
__global__ __launch_bounds__(256, 2) void conv_kernel(const ushort_t* __restrict__ xp,
                                                      const ushort_t* __restrict__ Wfb,
                                                      const float* __restrict__ bias,
                                                      float* __restrict__ out) {
    __shared__ alignas(16) ushort_t As[2 * 4 * 72 * 64];   // 72 KB (dbuf)

    const int pt   = blockIdx.x;        // 0..511
    const int ct   = blockIdx.y;        // 0..15
    const int b    = pt >> 4;
    const int h0   = (pt & 15) * 4;     // output rows h0..h0+3
    const int tid  = threadIdx.x;
    const int wv   = tid >> 6;
    const int lane = tid & 63;
    const int wrow = wv >> 1, wcol = wv & 1;   // px half (2 rows) / ch half
    const int quad = lane >> 4, lr = lane & 15;
    const int lsw  = ((lane & ~7) | ((lane ^ (lane >> 3)) & 7)) * 16;

    float4v acc[8][4];
    #pragma unroll
    for (int i = 0; i < 8; ++i)
        #pragma unroll
        for (int j = 0; j < 4; ++j) {
            float4v z = {0.f, 0.f, 0.f, 0.f};
            acc[i][j] = z;
        }

    const char* xpb = (const char*)xp;
    // Per-lane B base: ch' row = ct*128 + wcol*64 + j*16 + lr, cin chunk
    // (kk*4+quad)*8 elems -> bytes: ch*128 + j*2048 + kk*64 + quad*16.
    const char* wfb_w = (const char*)Wfb
        + (size_t)(ct * 128 + wcol * 64 + lr) * 128 + (size_t)quad * 16;

    auto stageA = [&](int dy) {
        // 4 rows x 9 KB = 36 chunks of 1 KB over 4 waves, into buffer dy&1
        char* dstb = (char*)As + (dy & 1) * 36864;
        #pragma unroll
        for (int k2 = 0; k2 < 9; ++k2) {
            const int c  = wv + 4 * k2;
            const int r  = c / 9;
            const int cs = c - 9 * r;
            const char* g = xpb
                + (size_t)((b * 72 + h0 + dy + r) * 72) * 128
                + (size_t)cs * 1024 + (size_t)lsw;
            __builtin_amdgcn_global_load_lds((gptr_t)g,
                (sptr_t)(dstb + c * 1024), 16, 0, 0);
        }
    };

    short8 w0[4], w1[4];   // B fragments: current-tap kk0 / kk1
    auto loadB = [&](const char* tb, int kk, short8* dst) {
        #pragma unroll
        for (int j = 0; j < 4; ++j)
            dst[j] = *(const short8*)(tb + j * 2048 + kk * 64);
    };

    stageA(0);
    loadB(wfb_w, 0, w0);                 // t=0, kk0

    for (int dy = 0; dy < 9; ++dy) {
        __syncthreads();                 // buf(dy) staged & visible; buf(dy+1) free
        if (dy < 8) stageA(dy + 1);      // latency hides under 9 taps of compute
        const ushort_t* Ab = As + (dy & 1) * 18432;
        const char* tb = wfb_w + (size_t)(dy * 9) * 262144;
        #pragma unroll
        for (int dx = 0; dx < 9; ++dx) {
            loadB(tb, 1, w1);            // kk1 frags of tap t, in flight

            const int akey  = (lr + dx) & 7;
            const int abase = (wrow * 2) * 72 + lr + dx;

            // ---- kk = 0 (operands w0) ----
            #pragma unroll
            for (int ih = 0; ih < 2; ++ih) {
                short8 a[4];
                #pragma unroll
                for (int ii = 0; ii < 4; ++ii)
                    a[ii] = *(const short8*)&Ab[(abase + ih * 72 + ii * 16) * 64
                                                + (quad ^ akey) * 8];
                #pragma unroll
                for (int ii = 0; ii < 4; ++ii)
                    #pragma unroll
                    for (int j = 0; j < 4; ++j)
                        acc[ih * 4 + ii][j] = __builtin_amdgcn_mfma_f32_16x16x32_bf16(
                            a[ii], w0[j], acc[ih * 4 + ii][j], 0, 0, 0);
            }

            // prefetch next tap's kk0 fragments (w0 just consumed)
            if (dy < 8 || dx < 8) loadB(tb + 262144, 0, w0);

            // ---- kk = 1 (operands w1) ----
            #pragma unroll
            for (int ih = 0; ih < 2; ++ih) {
                short8 a[4];
                #pragma unroll
                for (int ii = 0; ii < 4; ++ii)
                    a[ii] = *(const short8*)&Ab[(abase + ih * 72 + ii * 16) * 64
                                                + ((4 + quad) ^ akey) * 8];
                #pragma unroll
                for (int ii = 0; ii < 4; ++ii)
                    #pragma unroll
                    for (int j = 0; j < 4; ++j)
                        acc[ih * 4 + ii][j] = __builtin_amdgcn_mfma_f32_16x16x32_bf16(
                            a[ii], w1[j], acc[ih * 4 + ii][j], 0, 0, 0);
            }

            tb += 262144;
        }
    }

    // Epilogue: wave's 64 ch = 2 couts x 32 groups; 128 px = 2 output rows.
    const int c0 = ct * 4 + wcol * 2;
    const float bs0 = bias[c0], bs1 = bias[c0 + 1];
    #pragma unroll
    for (int i = 0; i < 8; ++i) {
        #pragma unroll
        for (int reg = 0; reg < 4; ++reg) {
            float v0 = acc[i][0][reg] * acc[i][0][reg] + acc[i][1][reg] * acc[i][1][reg];
            float v1 = acc[i][2][reg] * acc[i][2][reg] + acc[i][3][reg] * acc[i][3][reg];
            #pragma unroll
            for (int off = 1; off <= 8; off <<= 1) {
                v0 += __shfl_xor(v0, off, 64);
                v1 += __shfl_xor(v1, off, 64);
            }
            if (lr == 0) {
                const int w = (i & 3) * 16 + quad * 4 + reg;
                const int h = h0 + wrow * 2 + (i >> 2);
                out[((b * 64 + c0    ) * 64 + h) * 64 + w] = v0 + bs0;
                out[((b * 64 + c0 + 1) * 64 + h) * 64 + w] = v1 + bs1;
            }
        }
    }
}

// ---------------------------------------------------------------------------
extern "C" void kernel_launch(void* const* d_in, const int* in_sizes, int n_in,
                              void* d_out, int out_size, void* d_ws, size_t ws_size,
                              hipStream_t stream) {
    const float* x    = (const float*)d_in[0];
    const float* Tr   = (const float*)d_in[1];
    const float* Ti   = (const float*)d_in[2];
    const float* wr   = (const float*)d_in[3];
    const float* wi   = (const float*)d_in[4];
    const float* bias = (const float*)d_in[5];
    float* out = (float*)d_out;

    ushort_t* xp  = (ushort_t*)d_ws;                          // 21,233,664 B
    ushort_t* Wfb = (ushort_t*)((char*)d_ws + 21233664);      // 21,233,664 B

    pad_kernel<<<dim3(72, 32), 256, 0, stream>>>(x, xp);
    wf_kernel<<<dim3(32, 81), 256, 0, stream>>>(Tr, Ti, wr, wi, Wfb);
    conv_kernel<<<dim3(512, 16), 256, 0, stream>>>(xp, Wfb, bias, out);
}

// Round 2
// 2323.881 us; speedup vs baseline: 1.2359x; 1.2359x over previous
//
#include <hip/hip_runtime.h>
#include <stdint.h>

// ---------------------------------------------------------------------------
// BesselConv2d on MI355X (gfx950)
//
// k1: pad+convert x (fp32 NCHW) -> xp bf16 NHWC, zero-padded to 72x72.
// k2: build Wfb[tap][ch'][cin] bf16, ch' = cout*32 + (part*16+m).
// k3: implicit-GEMM conv, fused square/group-reduce/bias epilogue.
//
// R8 = R6 structure (Bs in LDS dbuf, per-tap barrier, verified 2060us)
// with the MFMA shape switched 16x16x32 -> 32x32x16:
//   - 32x32 pipe is ~15% faster per FLOP (2382-2495 TF vs 2075-2176 ubench)
//   - halves MFMA instruction count (32 vs 64 per tap per wave)
//   - LDS read traffic identical (16 A + 8 B ds_read_b128 per tap per wave)
//   - same 128 AGPR accumulator (4 px-tiles x 2 ch-tiles x f32x16)
// R7's B-in-VGPR experiment reverted: it spilled (+180MB scratch writes)
// and quadrupled L2 pressure (FETCH 606->1061MB). Back to LDS staging.
// Fragment layouts (K-chunk symmetry with verified 16x16x32 pattern):
//   A: lane l -> row=l&31, k=(l>>5)*8+i ; B: col=l&31, k=(l>>5)*8+i
//   C: col=l&31, row=(reg&3)+8*(reg>>2)+4*(l>>5)   [m74/m101 verified]
// ---------------------------------------------------------------------------

typedef unsigned short ushort_t;
typedef __attribute__((ext_vector_type(8))) short short8;     // 8 bf16 = 4 VGPRs
typedef __attribute__((ext_vector_type(16))) float float16v;  // 16 fp32 acc

typedef const void __attribute__((address_space(1)))* gptr_t;
typedef void __attribute__((address_space(3)))* sptr_t;

__device__ __forceinline__ ushort_t f2bf(float f) {
    union { float f; uint32_t u; } v; v.f = f;
    uint32_t u = v.u;
    u += 0x7fffu + ((u >> 16) & 1u);   // round-to-nearest-even
    return (ushort_t)(u >> 16);
}

// ---------------------------------------------------------------------------
// Kernel 1: x[32][64][64][64] (NCHW fp32) -> xp[32][72][72][64] (NHWC bf16)
// ---------------------------------------------------------------------------
__global__ __launch_bounds__(256) void pad_kernel(const float* __restrict__ x,
                                                  ushort_t* __restrict__ xp) {
    __shared__ float lds[64 * 65];
    const int hp  = blockIdx.x;   // 0..71
    const int b   = blockIdx.y;   // 0..31
    const int tid = threadIdx.x;
    const int h   = hp - 4;
    const bool hvalid = (h >= 0 && h < 64);
    if (hvalid) {
        #pragma unroll
        for (int it = 0; it < 16; ++it) {
            int idx = it * 256 + tid;
            int cin = idx >> 6, w = idx & 63;
            lds[w * 65 + cin] = x[((b * 64 + cin) * 64 + h) * 64 + w];
        }
    }
    __syncthreads();
    #pragma unroll
    for (int it = 0; it < 18; ++it) {
        int o = it * 256 + tid;
        int wp = o >> 6, cin = o & 63;
        int w = wp - 4;
        float val = (hvalid && w >= 0 && w < 64) ? lds[w * 65 + cin] : 0.0f;
        xp[((b * 72 + hp) * 72 + wp) * 64 + cin] = f2bf(val);
    }
}

// ---------------------------------------------------------------------------
// Kernel 2: Wfb[t][ch'][cin] bf16, ch' = cout*32 + g, g = part*16 + m.
// ---------------------------------------------------------------------------
__global__ __launch_bounds__(256) void wf_kernel(const float* __restrict__ Tr,
                                                 const float* __restrict__ Ti,
                                                 const float* __restrict__ wr,
                                                 const float* __restrict__ wi,
                                                 ushort_t* __restrict__ Wfb) {
    __shared__ float lds[64 * 65];
    const int g   = blockIdx.x;        // 0..31
    const int t   = blockIdx.y;        // 0..80
    const int part = g >> 4, m = g & 15;
    const int tid = threadIdx.x;
    #pragma unroll
    for (int it = 0; it < 16; ++it) {
        int cc = it * 256 + tid;       // cin*64 + cout
        float acc = 0.f;
        #pragma unroll
        for (int j = 0; j < 8; ++j) {
            float tr  = Tr[(m * 81 + t) * 8 + j];
            float ti  = Ti[(m * 81 + t) * 8 + j];
            float wrv = wr[(m * 8 + j) * 4096 + cc];
            float wiv = wi[(m * 8 + j) * 4096 + cc];
            acc += (part == 0) ? (tr * wrv - ti * wiv) : (tr * wiv + ti * wrv);
        }
        lds[(cc & 63) * 65 + (cc >> 6)] = acc;
    }
    __syncthreads();
    #pragma unroll
    for (int it = 0; it < 16; ++it) {
        int o = it * 256 + tid;        // cout*64 + cin
        int cout = o >> 6, cin = o & 63;
        Wfb[(t * 2048 + cout * 32 + g) * 64 + cin] = f2bf(lds[cout * 65 + cin]);
    }
}

// ---------------------------------------------------------------------------
// Kernel 3: implicit-GEMM conv.
// Block: 256 px (4 output rows) x 128 ch. Wave: 128 px x 64 ch.
// As: 4 padded rows [4][72][64] (XOR-16B-seg swizzled, key = px&7), per dy.
// Bs: double-buffered per-tap tile [2][128][64] (key = ch&7), prefetched.
// MFMA: 32x32x16 bf16; wave = 4 px-tiles (2 rows x 2 w-halves) x 2 ch-tiles.
// ---------------------------------------------------------------------------
__global__ __launch_bounds__(256, 2) void conv_kernel(const ushort_t* __restrict__ xp,
                                                      const ushort_t* __restrict__ Wfb,
                                                      const float* __restrict__ bias,
                                                      float* __restrict__ out) {
    __shared__ alignas(16) ushort_t As[4 * 72 * 64];       // 36 KB
    __shared__ alignas(16) ushort_t Bs[2 * 128 * 64];      // 32 KB (dbuf)

    const int pt   = blockIdx.x;        // 0..511
    const int ct   = blockIdx.y;        // 0..15
    const int b    = pt >> 4;
    const int h0   = (pt & 15) * 4;     // output rows h0..h0+3
    const int tid  = threadIdx.x;
    const int wv   = tid >> 6;
    const int lane = tid & 63;
    const int wrow = wv >> 1, wcol = wv & 1;   // px half (2 rows) / ch half
    const int ll   = lane & 31;                // M/N index within 32-tile
    const int hl   = lane >> 5;                // K-chunk selector
    const int lsw  = ((lane & ~7) | ((lane ^ (lane >> 3)) & 7)) * 16;

    float16v acc[4][2];
    #pragma unroll
    for (int i = 0; i < 4; ++i)
        #pragma unroll
        for (int j = 0; j < 2; ++j)
            acc[i][j] = (float16v)(0.f);

    const char* xpb  = (const char*)xp;
    const char* wfb0 = (const char*)Wfb + (size_t)(ct * 128) * 128;  // +t*262144

    auto stageA = [&](int dy) {
        // 4 rows x 9 KB = 36 chunks of 1 KB over 4 waves
        #pragma unroll
        for (int k2 = 0; k2 < 9; ++k2) {
            const int c  = wv + 4 * k2;
            const int r  = c / 9;
            const int cs = c - 9 * r;
            const char* g = xpb
                + (size_t)((b * 72 + h0 + dy + r) * 72) * 128
                + (size_t)cs * 1024 + (size_t)lsw;
            __builtin_amdgcn_global_load_lds((gptr_t)g,
                (sptr_t)((char*)As + c * 1024), 16, 0, 0);
        }
    };
    auto stageB = [&](int t) {
        const char* base = wfb0 + (size_t)t * 262144;
        char* dst = (char*)Bs + (t & 1) * 16384;
        #pragma unroll
        for (int k2 = 0; k2 < 4; ++k2) {
            const int c2 = wv * 4 + k2;
            __builtin_amdgcn_global_load_lds((gptr_t)(base + (size_t)c2 * 1024 + (size_t)lsw),
                (sptr_t)(dst + c2 * 1024), 16, 0, 0);
        }
    };

    stageA(0);
    stageB(0);

    const int bkey = ll & 7;
    for (int dy = 0; dy < 9; ++dy) {
        for (int dx = 0; dx < 9; ++dx) {
            const int t = dy * 9 + dx;
            __syncthreads();              // staging(t) drained; compute(t-1) done
            if (t < 80 && dx < 8) stageB(t + 1);   // prefetch next tap

            const ushort_t* Bp = Bs + (t & 1) * 8192;
            const int akey = (ll + dx) & 7;
            // A rows: LDS slot wrow*2+ih, px = iw*32 + ll + dx
            const int abase = (wrow * 2) * 72 + ll + dx;

            #pragma unroll
            for (int ks = 0; ks < 4; ++ks) {
                const int sa = ((ks * 2 + hl) ^ akey) * 8;
                const int sb = ((ks * 2 + hl) ^ bkey) * 8;
                short8 a[4], bb[2];
                #pragma unroll
                for (int j = 0; j < 2; ++j)
                    bb[j] = *(const short8*)&Bp[(wcol * 64 + j * 32 + ll) * 64 + sb];
                #pragma unroll
                for (int ih = 0; ih < 2; ++ih)
                    #pragma unroll
                    for (int iw = 0; iw < 2; ++iw)
                        a[ih * 2 + iw] = *(const short8*)
                            &As[(abase + ih * 72 + iw * 32) * 64 + sa];
                #pragma unroll
                for (int i = 0; i < 4; ++i)
                    #pragma unroll
                    for (int j = 0; j < 2; ++j)
                        acc[i][j] = __builtin_amdgcn_mfma_f32_32x32x16_bf16(
                            a[i], bb[j], acc[i][j], 0, 0, 0);
            }

            if (t < 80 && dx == 8) {
                __syncthreads();          // all waves done reading As(dy)
                stageA(dy + 1);
                stageB(t + 1);
            }
        }
    }

    // Epilogue: ch-tile j covers one cout's full 32 spectral groups (g = ll).
    // C layout: col=l&31 (g), row=(reg&3)+8*(reg>>2)+4*(l>>5) (w within tile).
    const int c0 = ct * 4 + wcol * 2;
    const float bs0 = bias[c0], bs1 = bias[c0 + 1];
    #pragma unroll
    for (int i = 0; i < 4; ++i) {
        const int ih = i >> 1, iw = i & 1;
        const int h  = h0 + wrow * 2 + ih;
        #pragma unroll
        for (int reg = 0; reg < 16; ++reg) {
            float v0 = acc[i][0][reg];
            float v1 = acc[i][1][reg];
            v0 *= v0; v1 *= v1;
            #pragma unroll
            for (int off = 1; off <= 16; off <<= 1) {
                v0 += __shfl_xor(v0, off, 64);
                v1 += __shfl_xor(v1, off, 64);
            }
            if (ll == 0) {
                const int w = iw * 32 + (reg & 3) + 8 * (reg >> 2) + 4 * hl;
                out[((b * 64 + c0    ) * 64 + h) * 64 + w] = v0 + bs0;
                out[((b * 64 + c0 + 1) * 64 + h) * 64 + w] = v1 + bs1;
            }
        }
    }
}

// ---------------------------------------------------------------------------
extern "C" void kernel_launch(void* const* d_in, const int* in_sizes, int n_in,
                              void* d_out, int out_size, void* d_ws, size_t ws_size,
                              hipStream_t stream) {
    const float* x    = (const float*)d_in[0];
    const float* Tr   = (const float*)d_in[1];
    const float* Ti   = (const float*)d_in[2];
    const float* wr   = (const float*)d_in[3];
    const float* wi   = (const float*)d_in[4];
    const float* bias = (const float*)d_in[5];
    float* out = (float*)d_out;

    ushort_t* xp  = (ushort_t*)d_ws;                          // 21,233,664 B
    ushort_t* Wfb = (ushort_t*)((char*)d_ws + 21233664);      // 21,233,664 B

    pad_kernel<<<dim3(72, 32), 256, 0, stream>>>(x, xp);
    wf_kernel<<<dim3(32, 81), 256, 0, stream>>>(Tr, Ti, wr, wi, Wfb);
    conv_kernel<<<dim3(512, 16), 256, 0, stream>>>(xp, Wfb, bias, out);
}

// Round 3
// 2255.221 us; speedup vs baseline: 1.2735x; 1.0304x over previous
//
#include <hip/hip_runtime.h>
#include <stdint.h>

// ---------------------------------------------------------------------------
// BesselConv2d on MI355X (gfx950)
//
// k1: pad+convert x (fp32 NCHW) -> xp bf16 NHWC, zero-padded to 72x72.
// k2: build Wfb[tap][ch'][cin] bf16, ch' = cout*32 + (part*16+m).
// k3: implicit-GEMM conv, fused square/group-reduce/bias epilogue.
//
// R9 = R6 base (16x16x32 MFMA, verified 2060us, 0 bank conflicts) +:
//  (1) As 5-row ring buffer (45KB): stage 1 new row/dy (9 chunks) instead
//      of 4 rows (36); removes the dx==8 double barrier (90->81 barriers);
//      xp re-reads /3.
//  (2) XCD-chunked block remap L=(bid&7)*1024+(bid>>3): each XCD's
//      resident cohort = 64 consecutive pt of one ct -> xp (2.6MB) + Wfb
//      tap tile (256KB) fit 4MB L2 -> stageB one-tap deadline is L2-hit.
// R8's 32x32 MFMA reverted: it produced +4 cyc/ds_read_b128 bank-conflict
// (2.5e8 cycles, mechanism unresolved) erasing the pipe-rate gain.
// R7's B-in-VGPR reverted earlier: spilled + 4x L2 pressure.
// ---------------------------------------------------------------------------

typedef unsigned short ushort_t;
typedef __attribute__((ext_vector_type(8))) short short8;   // 8 bf16 = 4 VGPRs
typedef __attribute__((ext_vector_type(4))) float float4v;  // 4 fp32 acc

typedef const void __attribute__((address_space(1)))* gptr_t;
typedef void __attribute__((address_space(3)))* sptr_t;

__device__ __forceinline__ ushort_t f2bf(float f) {
    union { float f; uint32_t u; } v; v.f = f;
    uint32_t u = v.u;
    u += 0x7fffu + ((u >> 16) & 1u);   // round-to-nearest-even
    return (ushort_t)(u >> 16);
}

// ---------------------------------------------------------------------------
// Kernel 1: x[32][64][64][64] (NCHW fp32) -> xp[32][72][72][64] (NHWC bf16)
// ---------------------------------------------------------------------------
__global__ __launch_bounds__(256) void pad_kernel(const float* __restrict__ x,
                                                  ushort_t* __restrict__ xp) {
    __shared__ float lds[64 * 65];
    const int hp  = blockIdx.x;   // 0..71
    const int b   = blockIdx.y;   // 0..31
    const int tid = threadIdx.x;
    const int h   = hp - 4;
    const bool hvalid = (h >= 0 && h < 64);
    if (hvalid) {
        #pragma unroll
        for (int it = 0; it < 16; ++it) {
            int idx = it * 256 + tid;
            int cin = idx >> 6, w = idx & 63;
            lds[w * 65 + cin] = x[((b * 64 + cin) * 64 + h) * 64 + w];
        }
    }
    __syncthreads();
    #pragma unroll
    for (int it = 0; it < 18; ++it) {
        int o = it * 256 + tid;
        int wp = o >> 6, cin = o & 63;
        int w = wp - 4;
        float val = (hvalid && w >= 0 && w < 64) ? lds[w * 65 + cin] : 0.0f;
        xp[((b * 72 + hp) * 72 + wp) * 64 + cin] = f2bf(val);
    }
}

// ---------------------------------------------------------------------------
// Kernel 2: Wfb[t][ch'][cin] bf16, ch' = cout*32 + g, g = part*16 + m.
// ---------------------------------------------------------------------------
__global__ __launch_bounds__(256) void wf_kernel(const float* __restrict__ Tr,
                                                 const float* __restrict__ Ti,
                                                 const float* __restrict__ wr,
                                                 const float* __restrict__ wi,
                                                 ushort_t* __restrict__ Wfb) {
    __shared__ float lds[64 * 65];
    const int g   = blockIdx.x;        // 0..31
    const int t   = blockIdx.y;        // 0..80
    const int part = g >> 4, m = g & 15;
    const int tid = threadIdx.x;
    #pragma unroll
    for (int it = 0; it < 16; ++it) {
        int cc = it * 256 + tid;       // cin*64 + cout
        float acc = 0.f;
        #pragma unroll
        for (int j = 0; j < 8; ++j) {
            float tr  = Tr[(m * 81 + t) * 8 + j];
            float ti  = Ti[(m * 81 + t) * 8 + j];
            float wrv = wr[(m * 8 + j) * 4096 + cc];
            float wiv = wi[(m * 8 + j) * 4096 + cc];
            acc += (part == 0) ? (tr * wrv - ti * wiv) : (tr * wiv + ti * wrv);
        }
        lds[(cc & 63) * 65 + (cc >> 6)] = acc;
    }
    __syncthreads();
    #pragma unroll
    for (int it = 0; it < 16; ++it) {
        int o = it * 256 + tid;        // cout*64 + cin
        int cout = o >> 6, cin = o & 63;
        Wfb[(t * 2048 + cout * 32 + g) * 64 + cin] = f2bf(lds[cout * 65 + cin]);
    }
}

// ---------------------------------------------------------------------------
// Kernel 3: implicit-GEMM conv.
// Block: 256 px (4 output rows) x 128 ch. Wave: 128 px x 64 ch.
// As: 5-row ring [5][72][64] (XOR-16B-seg swizzled, key = px&7); stage 1
//     new row per dy with a 9-tap completion deadline.
// Bs: double-buffered per-tap tile [2][128][64] (key = ch&7), prefetched.
// Grid: 1-D 8192, XCD-chunked remap for L2 locality.
// ---------------------------------------------------------------------------
__global__ __launch_bounds__(256, 2) void conv_kernel(const ushort_t* __restrict__ xp,
                                                      const ushort_t* __restrict__ Wfb,
                                                      const float* __restrict__ bias,
                                                      float* __restrict__ out) {
    __shared__ alignas(16) ushort_t As[5 * 72 * 64];       // 45 KB ring
    __shared__ alignas(16) ushort_t Bs[2 * 128 * 64];      // 32 KB (dbuf)

    const int bid = blockIdx.x;                 // 0..8191
    const int L   = (bid & 7) * 1024 + (bid >> 3);   // XCD-chunked, bijective
    const int ct  = L >> 9;                     // 0..15
    const int pt  = L & 511;                    // 0..511
    const int b   = pt >> 4;
    const int h0  = (pt & 15) * 4;              // output rows h0..h0+3
    const int tid  = threadIdx.x;
    const int wv   = tid >> 6;
    const int lane = tid & 63;
    const int wrow = wv >> 1, wcol = wv & 1;    // px half (2 rows) / ch half
    const int quad = lane >> 4, lr = lane & 15;
    const int lsw  = ((lane & ~7) | ((lane ^ (lane >> 3)) & 7)) * 16;

    float4v acc[8][4];
    #pragma unroll
    for (int i = 0; i < 8; ++i)
        #pragma unroll
        for (int j = 0; j < 4; ++j) {
            float4v z = {0.f, 0.f, 0.f, 0.f};
            acc[i][j] = z;
        }

    const char* xpb  = (const char*)xp;
    const char* wfb0 = (const char*)Wfb + (size_t)(ct * 128) * 128;  // +t*262144

    // Stage one padded input row (relative row rho, abs row h0+rho) into
    // ring slot rho%5. 9 chunks of 1 KB over 4 waves (wv0 gets 3).
    auto stageA = [&](int rho) {
        const int slot = rho >= 10 ? rho - 10 : (rho >= 5 ? rho - 5 : rho);
        char* dstb = (char*)As + slot * 9216;
        const char* gb = xpb + (size_t)(b * 72 + h0 + rho) * 9216;
        #pragma unroll
        for (int k = 0; k < 3; ++k) {
            const int cs = wv + 4 * k;
            if (cs < 9)
                __builtin_amdgcn_global_load_lds((gptr_t)(gb + (size_t)cs * 1024 + (size_t)lsw),
                    (sptr_t)(dstb + cs * 1024), 16, 0, 0);
        }
    };
    auto stageB = [&](int t) {
        const char* base = wfb0 + (size_t)t * 262144;
        char* dst = (char*)Bs + (t & 1) * 16384;
        #pragma unroll
        for (int k2 = 0; k2 < 4; ++k2) {
            const int c2 = wv * 4 + k2;
            __builtin_amdgcn_global_load_lds((gptr_t)(base + (size_t)c2 * 1024 + (size_t)lsw),
                (sptr_t)(dst + c2 * 1024), 16, 0, 0);
        }
    };

    stageA(0); stageA(1); stageA(2); stageA(3);
    stageB(0);

    const int bkey = lr & 7;
    for (int dy = 0; dy < 9; ++dy) {
        // ring slots for this wave's two A rows (wave-uniform)
        const int r0  = dy + wrow * 2;
        const int r1  = r0 + 1;
        const int rs0 = r0 >= 10 ? r0 - 10 : (r0 >= 5 ? r0 - 5 : r0);
        const int rs1 = r1 >= 10 ? r1 - 10 : (r1 >= 5 ? r1 - 5 : r1);
        for (int dx = 0; dx < 9; ++dx) {
            const int t = dy * 9 + dx;
            __syncthreads();              // staging(t) drained; compute(t-1) done
            if (t < 80) stageB(t + 1);    // prefetch next tap (other buffer)
            if (dx == 0 && dy < 8) stageA(dy + 4);   // 9-tap deadline

            const ushort_t* Bp = Bs + (t & 1) * 8192;
            const int akey = (lr + dx) & 7;
            const int pxb  = lr + dx;
            #pragma unroll
            for (int kk = 0; kk < 2; ++kk) {
                short8 a[8], bb[4];
                const int aslot = ((kk * 4 + quad) ^ akey) * 8;
                const int bslot = ((kk * 4 + quad) ^ bkey) * 8;
                #pragma unroll
                for (int j = 0; j < 4; ++j)
                    bb[j] = *(const short8*)&Bp[(wcol * 64 + j * 16 + lr) * 64 + bslot];
                #pragma unroll
                for (int i = 0; i < 8; ++i) {
                    const int rs = (i >> 2) ? rs1 : rs0;
                    a[i] = *(const short8*)&As[(rs * 72 + pxb + (i & 3) * 16) * 64 + aslot];
                }
                #pragma unroll
                for (int i = 0; i < 8; ++i)
                    #pragma unroll
                    for (int j = 0; j < 4; ++j)
                        acc[i][j] = __builtin_amdgcn_mfma_f32_16x16x32_bf16(
                            a[i], bb[j], acc[i][j], 0, 0, 0);
            }
        }
    }

    // Epilogue: wave's 64 ch = 2 couts x 32 groups; 128 px = 2 output rows.
    const int c0 = ct * 4 + wcol * 2;
    const float b0 = bias[c0], b1 = bias[c0 + 1];
    #pragma unroll
    for (int i = 0; i < 8; ++i) {
        #pragma unroll
        for (int reg = 0; reg < 4; ++reg) {
            float v0 = acc[i][0][reg] * acc[i][0][reg] + acc[i][1][reg] * acc[i][1][reg];
            float v1 = acc[i][2][reg] * acc[i][2][reg] + acc[i][3][reg] * acc[i][3][reg];
            #pragma unroll
            for (int off = 1; off <= 8; off <<= 1) {
                v0 += __shfl_xor(v0, off, 64);
                v1 += __shfl_xor(v1, off, 64);
            }
            if (lr == 0) {
                const int w = (i & 3) * 16 + quad * 4 + reg;
                const int h = h0 + wrow * 2 + (i >> 2);
                out[((b * 64 + c0    ) * 64 + h) * 64 + w] = v0 + b0;
                out[((b * 64 + c0 + 1) * 64 + h) * 64 + w] = v1 + b1;
            }
        }
    }
}

// ---------------------------------------------------------------------------
extern "C" void kernel_launch(void* const* d_in, const int* in_sizes, int n_in,
                              void* d_out, int out_size, void* d_ws, size_t ws_size,
                              hipStream_t stream) {
    const float* x    = (const float*)d_in[0];
    const float* Tr   = (const float*)d_in[1];
    const float* Ti   = (const float*)d_in[2];
    const float* wr   = (const float*)d_in[3];
    const float* wi   = (const float*)d_in[4];
    const float* bias = (const float*)d_in[5];
    float* out = (float*)d_out;

    ushort_t* xp  = (ushort_t*)d_ws;                          // 21,233,664 B
    ushort_t* Wfb = (ushort_t*)((char*)d_ws + 21233664);      // 21,233,664 B

    pad_kernel<<<dim3(72, 32), 256, 0, stream>>>(x, xp);
    wf_kernel<<<dim3(32, 81), 256, 0, stream>>>(Tr, Ti, wr, wi, Wfb);
    conv_kernel<<<dim3(8192), 256, 0, stream>>>(xp, Wfb, bias, out);
}

// Round 4
// 2081.014 us; speedup vs baseline: 1.3801x; 1.0837x over previous
//
#include <hip/hip_runtime.h>
#include <stdint.h>

// ---------------------------------------------------------------------------
// BesselConv2d on MI355X (gfx950)
//
// k1: pad+convert x (fp32 NCHW) -> xp bf16 NHWC, zero-padded to 72x72.
// k2: build Wfb[tap][ch'][cin] bf16, ch' = cout*32 + (part*16+m).
// k3: implicit-GEMM conv, fused square/group-reduce/bias epilogue.
//
// R10 = R6 byte-identical compute structure (16x16x32 MFMA, As 4-row
// staging, Bs dbuf, per-tap barrier; verified 2060us, VGPR 104, 0
// conflicts, no spill) + XCD-chunked block remap ONLY:
//   L=(bid&7)*1024+(bid>>3)  (bijective, 8192%8==0, m157 pattern)
//   -> each XCD's resident cohort = consecutive pt of one ct
//   -> 4 full xp images (2.6MB) + ct's Wfb slice (1.3MB) fit 4MB L2
//   -> stageA/stageB per-tap deadlines become L2-hit latency.
// R9's 5-row ring reverted: runtime ring bases spilled a[]/bb[] to
// scratch (WRITE 33->401MB == 45KB/block == the fragment arrays).
// R8's 32x32 MFMA reverted: +4cyc/ds_read bank conflict (2.5e8 cyc).
// R7's B-in-VGPR reverted: spill + 4x L2 pressure.
// ---------------------------------------------------------------------------

typedef unsigned short ushort_t;
typedef __attribute__((ext_vector_type(8))) short short8;   // 8 bf16 = 4 VGPRs
typedef __attribute__((ext_vector_type(4))) float float4v;  // 4 fp32 acc

typedef const void __attribute__((address_space(1)))* gptr_t;
typedef void __attribute__((address_space(3)))* sptr_t;

__device__ __forceinline__ ushort_t f2bf(float f) {
    union { float f; uint32_t u; } v; v.f = f;
    uint32_t u = v.u;
    u += 0x7fffu + ((u >> 16) & 1u);   // round-to-nearest-even
    return (ushort_t)(u >> 16);
}

// ---------------------------------------------------------------------------
// Kernel 1: x[32][64][64][64] (NCHW fp32) -> xp[32][72][72][64] (NHWC bf16)
// ---------------------------------------------------------------------------
__global__ __launch_bounds__(256) void pad_kernel(const float* __restrict__ x,
                                                  ushort_t* __restrict__ xp) {
    __shared__ float lds[64 * 65];
    const int hp  = blockIdx.x;   // 0..71
    const int b   = blockIdx.y;   // 0..31
    const int tid = threadIdx.x;
    const int h   = hp - 4;
    const bool hvalid = (h >= 0 && h < 64);
    if (hvalid) {
        #pragma unroll
        for (int it = 0; it < 16; ++it) {
            int idx = it * 256 + tid;
            int cin = idx >> 6, w = idx & 63;
            lds[w * 65 + cin] = x[((b * 64 + cin) * 64 + h) * 64 + w];
        }
    }
    __syncthreads();
    #pragma unroll
    for (int it = 0; it < 18; ++it) {
        int o = it * 256 + tid;
        int wp = o >> 6, cin = o & 63;
        int w = wp - 4;
        float val = (hvalid && w >= 0 && w < 64) ? lds[w * 65 + cin] : 0.0f;
        xp[((b * 72 + hp) * 72 + wp) * 64 + cin] = f2bf(val);
    }
}

// ---------------------------------------------------------------------------
// Kernel 2: Wfb[t][ch'][cin] bf16, ch' = cout*32 + g, g = part*16 + m.
// ---------------------------------------------------------------------------
__global__ __launch_bounds__(256) void wf_kernel(const float* __restrict__ Tr,
                                                 const float* __restrict__ Ti,
                                                 const float* __restrict__ wr,
                                                 const float* __restrict__ wi,
                                                 ushort_t* __restrict__ Wfb) {
    __shared__ float lds[64 * 65];
    const int g   = blockIdx.x;        // 0..31
    const int t   = blockIdx.y;        // 0..80
    const int part = g >> 4, m = g & 15;
    const int tid = threadIdx.x;
    #pragma unroll
    for (int it = 0; it < 16; ++it) {
        int cc = it * 256 + tid;       // cin*64 + cout
        float acc = 0.f;
        #pragma unroll
        for (int j = 0; j < 8; ++j) {
            float tr  = Tr[(m * 81 + t) * 8 + j];
            float ti  = Ti[(m * 81 + t) * 8 + j];
            float wrv = wr[(m * 8 + j) * 4096 + cc];
            float wiv = wi[(m * 8 + j) * 4096 + cc];
            acc += (part == 0) ? (tr * wrv - ti * wiv) : (tr * wiv + ti * wrv);
        }
        lds[(cc & 63) * 65 + (cc >> 6)] = acc;
    }
    __syncthreads();
    #pragma unroll
    for (int it = 0; it < 16; ++it) {
        int o = it * 256 + tid;        // cout*64 + cin
        int cout = o >> 6, cin = o & 63;
        Wfb[(t * 2048 + cout * 32 + g) * 64 + cin] = f2bf(lds[cout * 65 + cin]);
    }
}

// ---------------------------------------------------------------------------
// Kernel 3: implicit-GEMM conv.
// Block: 256 px (4 output rows) x 128 ch. Wave: 128 px x 64 ch.
// As: 4 padded rows [4][72][64] (XOR-16B-seg swizzled, key = px&7), per dy.
// Bs: double-buffered per-tap tile [2][128][64] (key = ch&7), prefetched.
// Grid: 1-D 8192, XCD-chunked remap for L2 locality.
// ---------------------------------------------------------------------------
__global__ __launch_bounds__(256, 2) void conv_kernel(const ushort_t* __restrict__ xp,
                                                      const ushort_t* __restrict__ Wfb,
                                                      const float* __restrict__ bias,
                                                      float* __restrict__ out) {
    __shared__ alignas(16) ushort_t As[4 * 72 * 64];       // 36 KB
    __shared__ alignas(16) ushort_t Bs[2 * 128 * 64];      // 32 KB (dbuf)

    const int bid = blockIdx.x;                      // 0..8191
    const int L   = (bid & 7) * 1024 + (bid >> 3);   // XCD-chunked, bijective
    const int ct  = L >> 9;                          // 0..15
    const int pt  = L & 511;                         // 0..511
    const int b    = pt >> 4;
    const int h0   = (pt & 15) * 4;     // output rows h0..h0+3
    const int tid  = threadIdx.x;
    const int wv   = tid >> 6;
    const int lane = tid & 63;
    const int wrow = wv >> 1, wcol = wv & 1;   // px half (2 rows) / ch half
    const int quad = lane >> 4, lr = lane & 15;
    const int lsw  = ((lane & ~7) | ((lane ^ (lane >> 3)) & 7)) * 16;

    float4v acc[8][4];
    #pragma unroll
    for (int i = 0; i < 8; ++i)
        #pragma unroll
        for (int j = 0; j < 4; ++j) {
            float4v z = {0.f, 0.f, 0.f, 0.f};
            acc[i][j] = z;
        }

    const char* xpb  = (const char*)xp;
    const char* wfb0 = (const char*)Wfb + (size_t)(ct * 128) * 128;  // +t*262144

    auto stageA = [&](int dy) {
        // 4 rows x 9 KB = 36 chunks of 1 KB over 4 waves
        #pragma unroll
        for (int k2 = 0; k2 < 9; ++k2) {
            const int c  = wv + 4 * k2;
            const int r  = c / 9;
            const int cs = c - 9 * r;
            const char* g = xpb
                + (size_t)((b * 72 + h0 + dy + r) * 72) * 128
                + (size_t)cs * 1024 + (size_t)lsw;
            __builtin_amdgcn_global_load_lds((gptr_t)g,
                (sptr_t)((char*)As + c * 1024), 16, 0, 0);
        }
    };
    auto stageB = [&](int t) {
        const char* base = wfb0 + (size_t)t * 262144;
        char* dst = (char*)Bs + (t & 1) * 16384;
        #pragma unroll
        for (int k2 = 0; k2 < 4; ++k2) {
            const int c2 = wv * 4 + k2;
            __builtin_amdgcn_global_load_lds((gptr_t)(base + (size_t)c2 * 1024 + (size_t)lsw),
                (sptr_t)(dst + c2 * 1024), 16, 0, 0);
        }
    };

    stageA(0);
    stageB(0);

    for (int dy = 0; dy < 9; ++dy) {
        for (int dx = 0; dx < 9; ++dx) {
            const int t = dy * 9 + dx;
            __syncthreads();              // staging(t) drained; compute(t-1) done
            if (t < 80 && dx < 8) stageB(t + 1);   // prefetch next tap

            const ushort_t* Bp = Bs + (t & 1) * 8192;
            const int akey = (lr + dx) & 7;
            const int bkey = lr & 7;
            // A rows for acc block i: As slot = wrow*2 + (i>>2), px = (i&3)*16+lr+dx
            const int abase = wrow * 2 * 72 + lr + dx;
            #pragma unroll
            for (int kk = 0; kk < 2; ++kk) {
                short8 a[8], bb[4];
                const int aslot = ((kk * 4 + quad) ^ akey) * 8;
                const int bslot = ((kk * 4 + quad) ^ bkey) * 8;
                #pragma unroll
                for (int j = 0; j < 4; ++j)
                    bb[j] = *(const short8*)&Bp[(wcol * 64 + j * 16 + lr) * 64 + bslot];
                #pragma unroll
                for (int i = 0; i < 8; ++i)
                    a[i] = *(const short8*)&As[(abase + (i >> 2) * 72 + (i & 3) * 16) * 64 + aslot];
                #pragma unroll
                for (int i = 0; i < 8; ++i)
                    #pragma unroll
                    for (int j = 0; j < 4; ++j)
                        acc[i][j] = __builtin_amdgcn_mfma_f32_16x16x32_bf16(
                            a[i], bb[j], acc[i][j], 0, 0, 0);
            }

            if (t < 80 && dx == 8) {
                __syncthreads();          // all waves done reading As(dy)
                stageA(dy + 1);
                stageB(t + 1);
            }
        }
    }

    // Epilogue: wave's 64 ch = 2 couts x 32 groups; 128 px = 2 output rows.
    const int c0 = ct * 4 + wcol * 2;
    const float b0 = bias[c0], b1 = bias[c0 + 1];
    #pragma unroll
    for (int i = 0; i < 8; ++i) {
        #pragma unroll
        for (int reg = 0; reg < 4; ++reg) {
            float v0 = acc[i][0][reg] * acc[i][0][reg] + acc[i][1][reg] * acc[i][1][reg];
            float v1 = acc[i][2][reg] * acc[i][2][reg] + acc[i][3][reg] * acc[i][3][reg];
            #pragma unroll
            for (int off = 1; off <= 8; off <<= 1) {
                v0 += __shfl_xor(v0, off, 64);
                v1 += __shfl_xor(v1, off, 64);
            }
            if (lr == 0) {
                const int w = (i & 3) * 16 + quad * 4 + reg;
                const int h = h0 + wrow * 2 + (i >> 2);
                out[((b * 64 + c0    ) * 64 + h) * 64 + w] = v0 + b0;
                out[((b * 64 + c0 + 1) * 64 + h) * 64 + w] = v1 + b1;
            }
        }
    }
}

// ---------------------------------------------------------------------------
extern "C" void kernel_launch(void* const* d_in, const int* in_sizes, int n_in,
                              void* d_out, int out_size, void* d_ws, size_t ws_size,
                              hipStream_t stream) {
    const float* x    = (const float*)d_in[0];
    const float* Tr   = (const float*)d_in[1];
    const float* Ti   = (const float*)d_in[2];
    const float* wr   = (const float*)d_in[3];
    const float* wi   = (const float*)d_in[4];
    const float* bias = (const float*)d_in[5];
    float* out = (float*)d_out;

    ushort_t* xp  = (ushort_t*)d_ws;                          // 21,233,664 B
    ushort_t* Wfb = (ushort_t*)((char*)d_ws + 21233664);      // 21,233,664 B

    pad_kernel<<<dim3(72, 32), 256, 0, stream>>>(x, xp);
    wf_kernel<<<dim3(32, 81), 256, 0, stream>>>(Tr, Ti, wr, wi, Wfb);
    conv_kernel<<<dim3(8192), 256, 0, stream>>>(xp, Wfb, bias, out);
}

// Round 5
// 1954.170 us; speedup vs baseline: 1.4697x; 1.0649x over previous
//
#include <hip/hip_runtime.h>
#include <stdint.h>

// ---------------------------------------------------------------------------
// BesselConv2d on MI355X (gfx950)
//
// k1: pad+convert x (fp32 NCHW) -> xp bf16 NHWC, zero-padded to 72x72.
// k2: build Wfb[tap][ch'][cin] bf16, ch' = cout*32 + (part*16+m).
// k3: implicit-GEMM conv, fused square/group-reduce/bias epilogue.
//
// R11 = R10 (R6 compute + XCD remap; 2081us, FETCH 288MB, 0 conflicts)
// + As 5-row ring with SPILL-FREE slot math:
//   - ring slots = wave-uniform incremental counters (readfirstlane-pinned,
//     conditional ++ per dy, never inside per-i indexing) -> no scratch
//     (R9's runtime-modulo ring spilled a[]/bb[]: WRITE 33->401MB).
//   - stage 1 new row/dy (9KB) instead of 4 rows (36KB): LDS write bytes
//     -75% on A, total LDS bytes -10% (LDS pipe is the saturated resource:
//     ~94 B/cyc demanded vs ~85-128 ceiling).
//   - removes the dx==8 double barrier: 90->81 barriers, stageA deadline
//     0 taps -> 1 tap (was a full-latency all-wave drain, ~3%).
// R8's 32x32 MFMA stays reverted (+4cyc/ds_read conflicts, unresolved).
// R7's B-in-VGPR stays reverted (spill + 4x L2 pressure).
// ---------------------------------------------------------------------------

typedef unsigned short ushort_t;
typedef __attribute__((ext_vector_type(8))) short short8;   // 8 bf16 = 4 VGPRs
typedef __attribute__((ext_vector_type(4))) float float4v;  // 4 fp32 acc

typedef const void __attribute__((address_space(1)))* gptr_t;
typedef void __attribute__((address_space(3)))* sptr_t;

__device__ __forceinline__ ushort_t f2bf(float f) {
    union { float f; uint32_t u; } v; v.f = f;
    uint32_t u = v.u;
    u += 0x7fffu + ((u >> 16) & 1u);   // round-to-nearest-even
    return (ushort_t)(u >> 16);
}

// ---------------------------------------------------------------------------
// Kernel 1: x[32][64][64][64] (NCHW fp32) -> xp[32][72][72][64] (NHWC bf16)
// ---------------------------------------------------------------------------
__global__ __launch_bounds__(256) void pad_kernel(const float* __restrict__ x,
                                                  ushort_t* __restrict__ xp) {
    __shared__ float lds[64 * 65];
    const int hp  = blockIdx.x;   // 0..71
    const int b   = blockIdx.y;   // 0..31
    const int tid = threadIdx.x;
    const int h   = hp - 4;
    const bool hvalid = (h >= 0 && h < 64);
    if (hvalid) {
        #pragma unroll
        for (int it = 0; it < 16; ++it) {
            int idx = it * 256 + tid;
            int cin = idx >> 6, w = idx & 63;
            lds[w * 65 + cin] = x[((b * 64 + cin) * 64 + h) * 64 + w];
        }
    }
    __syncthreads();
    #pragma unroll
    for (int it = 0; it < 18; ++it) {
        int o = it * 256 + tid;
        int wp = o >> 6, cin = o & 63;
        int w = wp - 4;
        float val = (hvalid && w >= 0 && w < 64) ? lds[w * 65 + cin] : 0.0f;
        xp[((b * 72 + hp) * 72 + wp) * 64 + cin] = f2bf(val);
    }
}

// ---------------------------------------------------------------------------
// Kernel 2: Wfb[t][ch'][cin] bf16, ch' = cout*32 + g, g = part*16 + m.
// ---------------------------------------------------------------------------
__global__ __launch_bounds__(256) void wf_kernel(const float* __restrict__ Tr,
                                                 const float* __restrict__ Ti,
                                                 const float* __restrict__ wr,
                                                 const float* __restrict__ wi,
                                                 ushort_t* __restrict__ Wfb) {
    __shared__ float lds[64 * 65];
    const int g   = blockIdx.x;        // 0..31
    const int t   = blockIdx.y;        // 0..80
    const int part = g >> 4, m = g & 15;
    const int tid = threadIdx.x;
    #pragma unroll
    for (int it = 0; it < 16; ++it) {
        int cc = it * 256 + tid;       // cin*64 + cout
        float acc = 0.f;
        #pragma unroll
        for (int j = 0; j < 8; ++j) {
            float tr  = Tr[(m * 81 + t) * 8 + j];
            float ti  = Ti[(m * 81 + t) * 8 + j];
            float wrv = wr[(m * 8 + j) * 4096 + cc];
            float wiv = wi[(m * 8 + j) * 4096 + cc];
            acc += (part == 0) ? (tr * wrv - ti * wiv) : (tr * wiv + ti * wrv);
        }
        lds[(cc & 63) * 65 + (cc >> 6)] = acc;
    }
    __syncthreads();
    #pragma unroll
    for (int it = 0; it < 16; ++it) {
        int o = it * 256 + tid;        // cout*64 + cin
        int cout = o >> 6, cin = o & 63;
        Wfb[(t * 2048 + cout * 32 + g) * 64 + cin] = f2bf(lds[cout * 65 + cin]);
    }
}

// ---------------------------------------------------------------------------
// Kernel 3: implicit-GEMM conv.
// Block: 256 px (4 output rows) x 128 ch. Wave: 128 px x 64 ch.
// As: 5-row ring [5][72][64] (XOR-16B-seg swizzled, key = px&7); stage the
//     single new row at dx==0 of each dy (slot via uniform counters).
// Bs: double-buffered per-tap tile [2][128][64] (key = ch&7), prefetched.
// Grid: 1-D 8192, XCD-chunked remap for L2 locality.
// ---------------------------------------------------------------------------
__global__ __launch_bounds__(256, 2) void conv_kernel(const ushort_t* __restrict__ xp,
                                                      const ushort_t* __restrict__ Wfb,
                                                      const float* __restrict__ bias,
                                                      float* __restrict__ out) {
    __shared__ alignas(16) ushort_t As[5 * 72 * 64];       // 45 KB ring
    __shared__ alignas(16) ushort_t Bs[2 * 128 * 64];      // 32 KB (dbuf)

    const int bid = blockIdx.x;                      // 0..8191
    const int L   = (bid & 7) * 1024 + (bid >> 3);   // XCD-chunked, bijective
    const int ct  = L >> 9;                          // 0..15
    const int pt  = L & 511;                         // 0..511
    const int b    = pt >> 4;
    const int h0   = (pt & 15) * 4;     // output rows h0..h0+3
    const int tid  = threadIdx.x;
    const int wv   = tid >> 6;
    const int lane = tid & 63;
    const int wrow = wv >> 1, wcol = wv & 1;   // px half (2 rows) / ch half
    const int quad = lane >> 4, lr = lane & 15;
    const int lsw  = ((lane & ~7) | ((lane ^ (lane >> 3)) & 7)) * 16;

    float4v acc[8][4];
    #pragma unroll
    for (int i = 0; i < 8; ++i)
        #pragma unroll
        for (int j = 0; j < 4; ++j) {
            float4v z = {0.f, 0.f, 0.f, 0.f};
            acc[i][j] = z;
        }

    const char* xpb  = (const char*)xp;
    const char* wfb0 = (const char*)Wfb + (size_t)(ct * 128) * 128;  // +t*262144

    // Stage one padded row (h0-relative row, ring slot). Both args are
    // wave-uniform runtime ints; 9 chunks of 1 KB over 4 waves.
    auto stageA = [&](int row, int slot) {
        char* dstb = (char*)As + slot * 9216;
        const char* gb = xpb + (size_t)(b * 72 + h0 + row) * 9216 + (size_t)lsw;
        __builtin_amdgcn_global_load_lds((gptr_t)(gb + (size_t)wv * 1024),
            (sptr_t)(dstb + wv * 1024), 16, 0, 0);
        __builtin_amdgcn_global_load_lds((gptr_t)(gb + (size_t)(wv + 4) * 1024),
            (sptr_t)(dstb + (wv + 4) * 1024), 16, 0, 0);
        if (wv == 0)
            __builtin_amdgcn_global_load_lds((gptr_t)(gb + (size_t)8 * 1024),
                (sptr_t)(dstb + 8 * 1024), 16, 0, 0);
    };
    auto stageB = [&](int t) {
        const char* base = wfb0 + (size_t)t * 262144;
        char* dst = (char*)Bs + (t & 1) * 16384;
        #pragma unroll
        for (int k2 = 0; k2 < 4; ++k2) {
            const int c2 = wv * 4 + k2;
            __builtin_amdgcn_global_load_lds((gptr_t)(base + (size_t)c2 * 1024 + (size_t)lsw),
                (sptr_t)(dst + c2 * 1024), 16, 0, 0);
        }
    };

    stageA(0, 0); stageA(1, 1); stageA(2, 2); stageA(3, 3);
    stageB(0);

    // Wave-uniform ring-slot counters (conditional ++ per dy, no modulo).
    const int wrowu = __builtin_amdgcn_readfirstlane(wrow);
    int s4  = 4;               // slot of row dy+4 (staged at dx==0)
    int rs0 = wrowu * 2;       // slot of this wave's first A row (dy+wrow*2)
    int rs1 = rs0 + 1;         // slot of second A row

    const int bkey = lr & 7;
    for (int dy = 0; dy < 9; ++dy) {
        const int ab0 = rs0 * 72;   // wave-uniform row bases
        const int ab1 = rs1 * 72;
        for (int dx = 0; dx < 9; ++dx) {
            const int t = dy * 9 + dx;
            __syncthreads();              // staging(t) drained; compute(t-1) done
            if (t < 80) stageB(t + 1);    // prefetch next tap (other buffer)
            if (dx == 0 && dy < 8) stageA(dy + 4, s4);   // 1-tap deadline

            const ushort_t* Bp = Bs + (t & 1) * 8192;
            const int akey = (lr + dx) & 7;
            const int pxb  = lr + dx;
            #pragma unroll
            for (int kk = 0; kk < 2; ++kk) {
                short8 a[8], bb[4];
                const int aslot = ((kk * 4 + quad) ^ akey) * 8;
                const int bslot = ((kk * 4 + quad) ^ bkey) * 8;
                #pragma unroll
                for (int j = 0; j < 4; ++j)
                    bb[j] = *(const short8*)&Bp[(wcol * 64 + j * 16 + lr) * 64 + bslot];
                #pragma unroll
                for (int i = 0; i < 8; ++i) {
                    const int ab = (i >> 2) ? ab1 : ab0;   // compile-time select
                    a[i] = *(const short8*)&As[(ab + pxb + (i & 3) * 16) * 64 + aslot];
                }
                #pragma unroll
                for (int i = 0; i < 8; ++i)
                    #pragma unroll
                    for (int j = 0; j < 4; ++j)
                        acc[i][j] = __builtin_amdgcn_mfma_f32_16x16x32_bf16(
                            a[i], bb[j], acc[i][j], 0, 0, 0);
            }
        }
        // advance ring (wave-uniform scalar math)
        s4  = (s4  == 4) ? 0 : s4  + 1;
        rs0 = (rs0 == 4) ? 0 : rs0 + 1;
        rs1 = (rs1 == 4) ? 0 : rs1 + 1;
    }

    // Epilogue: wave's 64 ch = 2 couts x 32 groups; 128 px = 2 output rows.
    const int c0 = ct * 4 + wcol * 2;
    const float b0 = bias[c0], b1 = bias[c0 + 1];
    #pragma unroll
    for (int i = 0; i < 8; ++i) {
        #pragma unroll
        for (int reg = 0; reg < 4; ++reg) {
            float v0 = acc[i][0][reg] * acc[i][0][reg] + acc[i][1][reg] * acc[i][1][reg];
            float v1 = acc[i][2][reg] * acc[i][2][reg] + acc[i][3][reg] * acc[i][3][reg];
            #pragma unroll
            for (int off = 1; off <= 8; off <<= 1) {
                v0 += __shfl_xor(v0, off, 64);
                v1 += __shfl_xor(v1, off, 64);
            }
            if (lr == 0) {
                const int w = (i & 3) * 16 + quad * 4 + reg;
                const int h = h0 + wrow * 2 + (i >> 2);
                out[((b * 64 + c0    ) * 64 + h) * 64 + w] = v0 + b0;
                out[((b * 64 + c0 + 1) * 64 + h) * 64 + w] = v1 + b1;
            }
        }
    }
}

// ---------------------------------------------------------------------------
extern "C" void kernel_launch(void* const* d_in, const int* in_sizes, int n_in,
                              void* d_out, int out_size, void* d_ws, size_t ws_size,
                              hipStream_t stream) {
    const float* x    = (const float*)d_in[0];
    const float* Tr   = (const float*)d_in[1];
    const float* Ti   = (const float*)d_in[2];
    const float* wr   = (const float*)d_in[3];
    const float* wi   = (const float*)d_in[4];
    const float* bias = (const float*)d_in[5];
    float* out = (float*)d_out;

    ushort_t* xp  = (ushort_t*)d_ws;                          // 21,233,664 B
    ushort_t* Wfb = (ushort_t*)((char*)d_ws + 21233664);      // 21,233,664 B

    pad_kernel<<<dim3(72, 32), 256, 0, stream>>>(x, xp);
    wf_kernel<<<dim3(32, 81), 256, 0, stream>>>(Tr, Ti, wr, wi, Wfb);
    conv_kernel<<<dim3(8192), 256, 0, stream>>>(xp, Wfb, bias, out);
}